// Round 1
// baseline (501.346 us; speedup 1.0000x reference)
//
#include <hip/hip_runtime.h>
#include <math.h>

#define N_ 4096

// ---------- workspace float offsets (lifetimes annotated; regions reused) ----
static constexpr size_t OFF_H0   = 0;        // h0 [4*N*64]; later h_1 [4*N*64]
static constexpr size_t OFF_HP0  = 1048576;  // h_0 [16*N*32]; later elu [4*N*128]
static constexpr size_t OFF_PP0  = 3145728;  // [16*4097*36]; later h1 at same base
static constexpr size_t OFF_PN0  = 5505600;  // [16*4097*36]
static constexpr size_t OFF_H1   = 3145728;  // h1 [4*N*128] (after PP0 dead)
static constexpr size_t OFF_PP1  = 5242880;  // [4*4097*68] (after PN0 dead)
static constexpr size_t OFF_PN1  = 6357264;  // [4*4097*68]
static constexpr size_t OFF_SS0  = 7865472;  // s_src0 [16*N]
static constexpr size_t OFF_SD0  = 7931008;  // s_dst0
static constexpr size_t OFF_SV0  = 7996544;  // sorted s_dst0
static constexpr size_t OFF_MD0  = 8062080;  // [16]
static constexpr size_t OFF_PERM0= 8062096;  // [16*N] u32
static constexpr size_t OFF_EP0  = 8127632;  // exp(v-md)
static constexpr size_t OFF_EN0  = 8193168;  // exp(0.2(v-md))
static constexpr size_t OFF_CBP0 = 8258704;  // chunk bases [16*64*36]
static constexpr size_t OFF_CBN0 = 8295568;
static constexpr size_t OFF_SS1  = 8332432;  // [4*N]
static constexpr size_t OFF_SD1  = 8348816;
static constexpr size_t OFF_SV1  = 8365200;
static constexpr size_t OFF_MD1  = 8381584;  // [4]
static constexpr size_t OFF_PERM1= 8381588;
static constexpr size_t OFF_EP1  = 8397972;
static constexpr size_t OFF_EN1  = 8414356;
static constexpr size_t OFF_CBP1 = 8430740;  // [4*64*68]
static constexpr size_t OFF_CBN1 = 8448148;  // total 8465556 floats ~= 33.9 MB

__device__ __forceinline__ unsigned f2s(float f){
  unsigned u=__float_as_uint(f);
  return u^((u&0x80000000u)?0xFFFFFFFFu:0x80000000u);
}
__device__ __forceinline__ float s2f(unsigned s){
  unsigned u=(s&0x80000000u)?(s^0x80000000u):~s;
  return __uint_as_float(u);
}

// ---------- instance norm over n axis: x[b][n][C] per (b,c) ------------------
template<int C>
__global__ void knorm(const float* __restrict__ x, float* __restrict__ y){
  int bc=blockIdx.x; int b=bc/C, c=bc%C;
  const float* xp=x+(size_t)b*N_*C+c;
  float s1=0.f,s2=0.f;
  for(int n=threadIdx.x;n<N_;n+=256){float v=xp[(size_t)n*C];s1+=v;s2+=v*v;}
  __shared__ float r1[256],r2[256];
  r1[threadIdx.x]=s1;r2[threadIdx.x]=s2;__syncthreads();
  for(int off=128;off>0;off>>=1){
    if(threadIdx.x<off){r1[threadIdx.x]+=r1[threadIdx.x+off];r2[threadIdx.x]+=r2[threadIdx.x+off];}
    __syncthreads();
  }
  float mean=r1[0]*(1.0f/N_);
  float var=r2[0]*(1.0f/N_)-mean*mean;
  float rstd=rsqrtf(var+1e-5f);
  float* yp=y+(size_t)b*N_*C+c;
  for(int n=threadIdx.x;n<N_;n+=256) yp[(size_t)n*C]=(xp[(size_t)n*C]-mean)*rstd;
}

// ---------- layer0 projection: h_0[p][n][32], s_src0/s_dst0[p][n] ------------
__global__ void kproj0(const float* __restrict__ h0, const float* __restrict__ w0,
                       const float* __restrict__ asrc, const float* __restrict__ adst,
                       float* __restrict__ hp, float* __restrict__ ss, float* __restrict__ sd){
  __shared__ float4 w4[4*64*8];
  __shared__ float4 av4[64]; // [0..31]=a_src[h][kq], [32..63]=a_dst
  int tid=threadIdx.x;
  const float4* wg=(const float4*)w0;
  for(int i=tid;i<2048;i+=256) w4[i]=wg[i];
  if(tid<32) av4[tid]=((const float4*)asrc)[tid];
  else if(tid<64) av4[tid]=((const float4*)adst)[tid-32];
  __syncthreads();
  int gid=blockIdx.x*256+tid;
  int b=gid>>14, n=(gid>>2)&4095, h=gid&3;
  const float4* hr4=(const float4*)(h0+((size_t)(b*N_+n))*64);
  float hrow[64];
  #pragma unroll
  for(int q=0;q<16;q++){float4 t=hr4[q];hrow[4*q]=t.x;hrow[4*q+1]=t.y;hrow[4*q+2]=t.z;hrow[4*q+3]=t.w;}
  float4 acc[8];
  #pragma unroll
  for(int q=0;q<8;q++) acc[q]=make_float4(0.f,0.f,0.f,0.f);
  #pragma unroll
  for(int d=0;d<64;d++){
    float hv=hrow[d];
    #pragma unroll
    for(int q=0;q<8;q++){float4 wv=w4[(h*64+d)*8+q];
      acc[q].x+=hv*wv.x;acc[q].y+=hv*wv.y;acc[q].z+=hv*wv.z;acc[q].w+=hv*wv.w;}
  }
  float ssv=0.f,sdv=0.f;
  #pragma unroll
  for(int q=0;q<8;q++){
    float4 a1=av4[h*8+q],a2=av4[32+h*8+q];
    ssv+=acc[q].x*a1.x+acc[q].y*a1.y+acc[q].z*a1.z+acc[q].w*a1.w;
    sdv+=acc[q].x*a2.x+acc[q].y*a2.y+acc[q].z*a2.z+acc[q].w*a2.w;
  }
  int p=b*4+h;
  float4* o4=(float4*)(hp+((size_t)p*N_+n)*32);
  #pragma unroll
  for(int q=0;q<8;q++) o4[q]=acc[q];
  ss[(size_t)p*N_+n]=ssv; sd[(size_t)p*N_+n]=sdv;
}

// ---------- per-pair bitonic sort of s_dst + exp tables ----------------------
__global__ void __launch_bounds__(1024) ksort(const float* __restrict__ sdst,
    float* __restrict__ sv, unsigned* __restrict__ permg, float* __restrict__ md,
    float* __restrict__ eP, float* __restrict__ eN){
  __shared__ unsigned keys[4096];
  __shared__ unsigned perm[4096];
  int p=blockIdx.x, tid=threadIdx.x;
  const float* s=sdst+(size_t)p*N_;
  for(int j=tid;j<4096;j+=1024){keys[j]=f2s(s[j]);perm[j]=(unsigned)j;}
  for(unsigned k=2;k<=4096u;k<<=1)
    for(unsigned j=k>>1;j>0;j>>=1){
      __syncthreads();
      for(unsigned idx=tid;idx<4096u;idx+=1024u){
        unsigned q=idx^j;
        if(q>idx){
          bool up=((idx&k)==0);
          unsigned a=keys[idx],b2=keys[q];
          if(up?(a>b2):(a<b2)){
            keys[idx]=b2;keys[q]=a;
            unsigned t=perm[idx];perm[idx]=perm[q];perm[q]=t;
          }
        }
      }
    }
  __syncthreads();
  float m=s2f(keys[4095]); // max (ascending sort)
  if(tid==0) md[p]=m;
  for(int r=tid;r<4096;r+=1024){
    float v=s2f(keys[r]);
    sv[(size_t)p*N_+r]=v;
    permg[(size_t)p*N_+r]=perm[r];
    eP[(size_t)p*N_+r]=expf(v-m);
    eN[(size_t)p*N_+r]=expf(0.2f*(v-m));
  }
}

// ---------- chunk sums (64-elem chunks) + chunk-level exclusive scan ---------
template<int D,int DPAD>
__global__ void __launch_bounds__(1024) kchunks(const unsigned* __restrict__ permg,
    const float* __restrict__ eP, const float* __restrict__ eN,
    const float* __restrict__ hmat, float* __restrict__ chbP, float* __restrict__ chbN,
    float* __restrict__ PP, float* __restrict__ PN){
  __shared__ unsigned permL[4096];
  __shared__ float chP[64*(D+1)],chN[64*(D+1)];
  int p=blockIdx.x,tid=threadIdx.x;
  for(int j=tid;j<4096;j+=1024) permL[j]=permg[(size_t)p*N_+j];
  __syncthreads();
  const float* hb=hmat+(size_t)p*N_*D;
  const float* ePb=eP+(size_t)p*N_;
  const float* eNb=eN+(size_t)p*N_;
  for(int tt=tid;tt<64*(D+1);tt+=1024){
    int c=tt/(D+1),kk=tt%(D+1);
    float sp=0.f,sn=0.f;
    int base=c*64;
    for(int q=0;q<64;q++){
      int r=base+q;
      float hv=(kk<D)?hb[(size_t)permL[r]*D+kk]:1.0f;
      sp+=ePb[r]*hv; sn+=eNb[r]*hv;
    }
    chP[tt]=sp;chN[tt]=sn;
  }
  __syncthreads();
  if(tid<D+1){
    float rp=0.f,rn=0.f;
    for(int c=0;c<64;c++){
      chbP[((size_t)p*64+c)*DPAD+tid]=rp;
      chbN[((size_t)p*64+c)*DPAD+tid]=rn;
      rp+=chP[c*(D+1)+tid];rn+=chN[c*(D+1)+tid];
    }
    PP[((size_t)p*4097+4096)*DPAD+tid]=rp; // totals row
    PN[((size_t)p*4097+4096)*DPAD+tid]=rn;
  }
}

// ---------- full per-rank exclusive prefix tables ----------------------------
template<int D,int DPAD>
__global__ void __launch_bounds__(1024) ktables(const unsigned* __restrict__ permg,
    const float* __restrict__ eP, const float* __restrict__ eN,
    const float* __restrict__ hmat, const float* __restrict__ chbP,
    const float* __restrict__ chbN, float* __restrict__ PP, float* __restrict__ PN){
  __shared__ unsigned permL[1024];
  __shared__ float ePL[1024],eNL[1024];
  int bx=blockIdx.x; int p=bx>>2, cg=bx&3; int tid=threadIdx.x;
  int r0=cg*1024;
  permL[tid]=permg[(size_t)p*N_+r0+tid];
  ePL[tid]=eP[(size_t)p*N_+r0+tid];
  eNL[tid]=eN[(size_t)p*N_+r0+tid];
  __syncthreads();
  const float* hb=hmat+(size_t)p*N_*D;
  for(int tt=tid;tt<16*(D+1);tt+=1024){
    int cl=tt/(D+1),kk=tt%(D+1);
    int c=cg*16+cl;
    float rp=chbP[((size_t)p*64+c)*DPAD+kk];
    float rn=chbN[((size_t)p*64+c)*DPAD+kk];
    int lbase=cl*64;
    for(int q=0;q<64;q++){
      int rl=lbase+q, rg=r0+rl;
      float hv=(kk<D)?hb[(size_t)permL[rl]*D+kk]:1.0f;
      PP[((size_t)p*4097+rg)*DPAD+kk]=rp;
      PN[((size_t)p*4097+rg)*DPAD+kk]=rn;
      rp+=ePL[rl]*hv; rn+=eNL[rl]*hv;
    }
  }
}

// ---------- layer0 row eval: softmax via prefix tables, +bias, ELU, concat ---
__global__ void keval0(const float* __restrict__ ss, const float* __restrict__ sv,
                       const float* __restrict__ md, const float* __restrict__ PP,
                       const float* __restrict__ PN, const float* __restrict__ bias,
                       float* __restrict__ out){
  int gid=blockIdx.x*256+threadIdx.x;
  int p=gid>>12, i=gid&4095;
  int b=p>>2,h=p&3;
  float ssrc=ss[(size_t)p*N_+i];
  float m=md[p];
  float xx=ssrc+m;
  float M=xx>0.f?xx:0.2f*xx;              // row max of leaky_relu scores
  float fpos=expf(xx-M), fneg=expf(0.2f*xx-M);
  float th=-ssrc;
  const float* svp=sv+(size_t)p*N_;
  int lo=0,hi=4096;
  while(lo<hi){int mid=(lo+hi)>>1; if(svp[mid]<=th) lo=mid+1; else hi=mid;}
  const float* ppr=PP+((size_t)p*4097+lo)*36;
  const float* pnr=PN+((size_t)p*4097+lo)*36;
  const float* ptr0=PP+((size_t)p*4097+4096)*36;
  float denom=fpos*(ptr0[32]-ppr[32])+fneg*pnr[32];
  float inv=1.0f/denom;
  float* op=out+((size_t)(b*N_+i))*128+h*32;
  #pragma unroll
  for(int q=0;q<8;q++){
    float4 a=((const float4*)ppr)[q],t=((const float4*)ptr0)[q],nn=((const float4*)pnr)[q];
    float4 r;
    r.x=(fpos*(t.x-a.x)+fneg*nn.x)*inv+bias[4*q+0];
    r.y=(fpos*(t.y-a.y)+fneg*nn.y)*inv+bias[4*q+1];
    r.z=(fpos*(t.z-a.z)+fneg*nn.z)*inv+bias[4*q+2];
    r.w=(fpos*(t.w-a.w)+fneg*nn.w)*inv+bias[4*q+3];
    r.x=r.x>0.f?r.x:expm1f(r.x);
    r.y=r.y>0.f?r.y:expm1f(r.y);
    r.z=r.z>0.f?r.z:expm1f(r.z);
    r.w=r.w>0.f?r.w:expm1f(r.w);
    ((float4*)op)[q]=r;
  }
}

// ---------- layer1 projection (s via folded w1@a) ----------------------------
__global__ void kproj1(const float* __restrict__ h1, const float* __restrict__ w1,
                       const float* __restrict__ asrc, const float* __restrict__ adst,
                       float* __restrict__ hp, float* __restrict__ ss, float* __restrict__ sd){
  __shared__ float4 w4[128*16];
  __shared__ float wa[128],wd[128];
  int tid=threadIdx.x;
  const float4* wg=(const float4*)w1;
  for(int i=tid;i<2048;i+=256) w4[i]=wg[i];
  if(tid<128){
    float s1=0.f,s2=0.f;
    for(int k=0;k<64;k++){float wv=w1[tid*64+k];s1+=wv*asrc[k];s2+=wv*adst[k];}
    wa[tid]=s1;wd[tid]=s2;
  }
  __syncthreads();
  int gid=blockIdx.x*256+tid;
  int b=gid>>14, n=(gid>>2)&4095, q4=gid&3;
  const float4* hr4=(const float4*)(h1+((size_t)(b*N_+n))*128);
  float hrow[128];
  #pragma unroll
  for(int q=0;q<32;q++){float4 t=hr4[q];hrow[4*q]=t.x;hrow[4*q+1]=t.y;hrow[4*q+2]=t.z;hrow[4*q+3]=t.w;}
  float4 acc[4];
  #pragma unroll
  for(int q=0;q<4;q++) acc[q]=make_float4(0.f,0.f,0.f,0.f);
  #pragma unroll
  for(int d=0;d<128;d++){
    float hv=hrow[d];
    #pragma unroll
    for(int q=0;q<4;q++){float4 wv=w4[d*16+q4*4+q];
      acc[q].x+=hv*wv.x;acc[q].y+=hv*wv.y;acc[q].z+=hv*wv.z;acc[q].w+=hv*wv.w;}
  }
  float4* o4=(float4*)(hp+((size_t)(b*N_+n))*64+q4*16);
  #pragma unroll
  for(int q=0;q<4;q++) o4[q]=acc[q];
  if(q4==0){
    float s1=0.f,s2=0.f;
    #pragma unroll
    for(int d=0;d<128;d++){s1+=hrow[d]*wa[d];s2+=hrow[d]*wd[d];}
    ss[(size_t)b*N_+n]=s1;sd[(size_t)b*N_+n]=s2;
  }
}

// ---------- layer1 row eval -> final output ----------------------------------
__global__ void keval1(const float* __restrict__ ss, const float* __restrict__ sv,
                       const float* __restrict__ md, const float* __restrict__ PP,
                       const float* __restrict__ PN, const float* __restrict__ bias,
                       float* __restrict__ out){
  int gid=blockIdx.x*256+threadIdx.x;
  int p=gid>>12, i=gid&4095;
  float ssrc=ss[(size_t)p*N_+i];
  float m=md[p];
  float xx=ssrc+m;
  float M=xx>0.f?xx:0.2f*xx;
  float fpos=expf(xx-M), fneg=expf(0.2f*xx-M);
  float th=-ssrc;
  const float* svp=sv+(size_t)p*N_;
  int lo=0,hi=4096;
  while(lo<hi){int mid=(lo+hi)>>1; if(svp[mid]<=th) lo=mid+1; else hi=mid;}
  const float* ppr=PP+((size_t)p*4097+lo)*68;
  const float* pnr=PN+((size_t)p*4097+lo)*68;
  const float* ptr0=PP+((size_t)p*4097+4096)*68;
  float denom=fpos*(ptr0[64]-ppr[64])+fneg*pnr[64];
  float inv=1.0f/denom;
  float* op=out+((size_t)p*N_+i)*64;
  #pragma unroll
  for(int q=0;q<16;q++){
    float4 a=((const float4*)ppr)[q],t=((const float4*)ptr0)[q],nn=((const float4*)pnr)[q];
    float4 r;
    r.x=(fpos*(t.x-a.x)+fneg*nn.x)*inv+bias[4*q+0];
    r.y=(fpos*(t.y-a.y)+fneg*nn.y)*inv+bias[4*q+1];
    r.z=(fpos*(t.z-a.z)+fneg*nn.z)*inv+bias[4*q+2];
    r.w=(fpos*(t.w-a.w)+fneg*nn.w)*inv+bias[4*q+3];
    ((float4*)op)[q]=r;
  }
}

extern "C" void kernel_launch(void* const* d_in, const int* in_sizes, int n_in,
                              void* d_out, int out_size, void* d_ws, size_t ws_size,
                              hipStream_t stream) {
  const float* x  =(const float*)d_in[0];
  const float* w0 =(const float*)d_in[1];
  const float* as0=(const float*)d_in[2];
  const float* ad0=(const float*)d_in[3];
  const float* b0 =(const float*)d_in[4];
  const float* w1 =(const float*)d_in[5];
  const float* as1=(const float*)d_in[6];
  const float* ad1=(const float*)d_in[7];
  const float* b1 =(const float*)d_in[8];
  float* ws=(float*)d_ws;
  float* out=(float*)d_out;

  float* h0   = ws+OFF_H0;
  float* hp0  = ws+OFF_HP0;
  float* PP0  = ws+OFF_PP0;
  float* PN0  = ws+OFF_PN0;
  float* elu  = ws+OFF_HP0;   // reuse (h_0 dead after tables)
  float* h1   = ws+OFF_H1;    // reuse (PP0 dead after eval0)
  float* hp1  = ws+OFF_H0;    // reuse (h0 dead after proj0)
  float* PP1  = ws+OFF_PP1;
  float* PN1  = ws+OFF_PN1;
  float* ss0  = ws+OFF_SS0;  float* sd0 = ws+OFF_SD0;
  float* sv0  = ws+OFF_SV0;  float* md0 = ws+OFF_MD0;
  unsigned* pm0=(unsigned*)(ws+OFF_PERM0);
  float* eP0  = ws+OFF_EP0;  float* eN0 = ws+OFF_EN0;
  float* cbP0 = ws+OFF_CBP0; float* cbN0= ws+OFF_CBN0;
  float* ss1  = ws+OFF_SS1;  float* sd1 = ws+OFF_SD1;
  float* sv1  = ws+OFF_SV1;  float* md1 = ws+OFF_MD1;
  unsigned* pm1=(unsigned*)(ws+OFF_PERM1);
  float* eP1  = ws+OFF_EP1;  float* eN1 = ws+OFF_EN1;
  float* cbP1 = ws+OFF_CBP1; float* cbN1= ws+OFF_CBN1;

  // ---- layer 0 ----
  knorm<64><<<256,256,0,stream>>>(x,h0);
  kproj0<<<256,256,0,stream>>>(h0,w0,as0,ad0,hp0,ss0,sd0);
  ksort<<<16,1024,0,stream>>>(sd0,sv0,pm0,md0,eP0,eN0);
  kchunks<32,36><<<16,1024,0,stream>>>(pm0,eP0,eN0,hp0,cbP0,cbN0,PP0,PN0);
  ktables<32,36><<<64,1024,0,stream>>>(pm0,eP0,eN0,hp0,cbP0,cbN0,PP0,PN0);
  keval0<<<256,256,0,stream>>>(ss0,sv0,md0,PP0,PN0,b0,elu);
  // ---- layer 1 ----
  knorm<128><<<512,256,0,stream>>>(elu,h1);
  kproj1<<<256,256,0,stream>>>(h1,w1,as1,ad1,hp1,ss1,sd1);
  ksort<<<4,1024,0,stream>>>(sd1,sv1,pm1,md1,eP1,eN1);
  kchunks<64,68><<<4,1024,0,stream>>>(pm1,eP1,eN1,hp1,cbP1,cbN1,PP1,PN1);
  ktables<64,68><<<16,1024,0,stream>>>(pm1,eP1,eN1,hp1,cbP1,cbN1,PP1,PN1);
  keval1<<<64,256,0,stream>>>(ss1,sv1,md1,PP1,PN1,b1,out);
}

// Round 2
// 475.868 us; speedup vs baseline: 1.0535x; 1.0535x over previous
//
#include <hip/hip_runtime.h>
#include <math.h>

#define N_ 4096

// ---------------- workspace float offsets -----------------------------------
static constexpr size_t OFF_STATS0 = 0;        // [4][64][2]  = 512
static constexpr size_t OFF_STATS1 = 512;      // [4][128][2] = 1024  (memset 1536 floats)
static constexpr size_t OFF_HP0    = 2048;     // [16][4096][32] = 2097152
static constexpr size_t OFF_SS0    = 2099200;  // [16][4096]
static constexpr size_t OFF_SD0    = 2164736;
static constexpr size_t OFF_RUNS0  = 2230272;  // u64[16][4096] -> 131072 floats
static constexpr size_t OFF_SV0    = 2361344;
static constexpr size_t OFF_PM0    = 2426880;  // u32
static constexpr size_t OFF_EP0    = 2492416;
static constexpr size_t OFF_EN0    = 2557952;
static constexpr size_t OFF_BP0    = 2623488;  // [16][129][36] = 74304
static constexpr size_t OFF_BN0    = 2697792;
static constexpr size_t OFF_ELU    = 2772096;  // [4][4096][128] = 2097152
static constexpr size_t OFF_HP1    = 4869248;  // [4][4096][64] = 1048576
static constexpr size_t OFF_SS1    = 5917824;  // [4][4096]
static constexpr size_t OFF_SD1    = 5934208;
static constexpr size_t OFF_RUNS1  = 5950592;  // u64[4][4096] -> 32768 floats
static constexpr size_t OFF_SV1    = 5983360;
static constexpr size_t OFF_PM1    = 5999744;
static constexpr size_t OFF_EP1    = 6016128;
static constexpr size_t OFF_EN1    = 6032512;
static constexpr size_t OFF_BP1    = 6048896;  // [4][129][68] = 35088
static constexpr size_t OFF_BN1    = 6083984;  // end 6119072 floats = 24.5 MB

__device__ __forceinline__ unsigned f2s(float f){
  unsigned u=__float_as_uint(f);
  return u^((u&0x80000000u)?0xFFFFFFFFu:0x80000000u);
}
__device__ __forceinline__ float s2f(unsigned s){
  unsigned u=(s&0x80000000u)?(s^0x80000000u):~s;
  return __uint_as_float(u);
}

// ---------- partial stats (coalesced) + atomic accumulate --------------------
template<int C>
__global__ void kstats(const float* __restrict__ x, float* __restrict__ stats){
  // grid: B*32 blocks, 256 threads; block covers 128 rows of one b
  int blk=blockIdx.x; int b=blk>>5, seg=blk&31;
  int tid=threadIdx.x;
  const int RPT=256/C;       // row-lanes per iteration
  const int IT=128/RPT;
  int c=tid%C, rl=tid/C;
  const float* xb=x+(size_t)b*N_*C;
  float s1=0.f,s2=0.f;
  int r0=seg*128+rl;
  for(int i=0;i<IT;i++){
    float v=xb[(size_t)(r0+i*RPT)*C+c];
    s1+=v;s2+=v*v;
  }
  __shared__ float sh1[256],sh2[256];
  sh1[tid]=s1;sh2[tid]=s2;__syncthreads();
  if(tid<C){
    float a1=0.f,a2=0.f;
    for(int g=0;g<RPT;g++){a1+=sh1[g*C+tid];a2+=sh2[g*C+tid];}
    atomicAdd(&stats[(size_t)(b*C+tid)*2+0],a1);
    atomicAdd(&stats[(size_t)(b*C+tid)*2+1],a2);
  }
}

// ---------- layer0 projection with inline instance-norm ----------------------
__global__ void kproj0(const float* __restrict__ x, const float* __restrict__ stats,
                       const float* __restrict__ w0, const float* __restrict__ asrc,
                       const float* __restrict__ adst, float* __restrict__ hp,
                       float* __restrict__ ss, float* __restrict__ sd){
  __shared__ float4 w4[2048];
  __shared__ float4 av4[64];
  __shared__ float mean[64],rstd[64];
  int tid=threadIdx.x;
  const float4* wg=(const float4*)w0;
  for(int i=tid;i<2048;i+=256) w4[i]=wg[i];
  if(tid<32) av4[tid]=((const float4*)asrc)[tid];
  else if(tid<64) av4[tid]=((const float4*)adst)[tid-32];
  int gid=blockIdx.x*256+tid;
  int b=gid>>14;
  if(tid<64){
    float s1=stats[(size_t)(b*64+tid)*2+0],s2=stats[(size_t)(b*64+tid)*2+1];
    float mu=s1*(1.0f/N_);
    float var=s2*(1.0f/N_)-mu*mu;
    mean[tid]=mu; rstd[tid]=rsqrtf(var+1e-5f);
  }
  __syncthreads();
  int n=(gid>>2)&4095, h=gid&3;
  const float4* hr4=(const float4*)(x+((size_t)(b*N_+n))*64);
  float hrow[64];
  #pragma unroll
  for(int q=0;q<16;q++){
    float4 t=hr4[q];
    hrow[4*q+0]=(t.x-mean[4*q+0])*rstd[4*q+0];
    hrow[4*q+1]=(t.y-mean[4*q+1])*rstd[4*q+1];
    hrow[4*q+2]=(t.z-mean[4*q+2])*rstd[4*q+2];
    hrow[4*q+3]=(t.w-mean[4*q+3])*rstd[4*q+3];
  }
  float4 acc[8];
  #pragma unroll
  for(int q=0;q<8;q++) acc[q]=make_float4(0.f,0.f,0.f,0.f);
  #pragma unroll
  for(int d=0;d<64;d++){
    float hv=hrow[d];
    #pragma unroll
    for(int q=0;q<8;q++){float4 wv=w4[(h*64+d)*8+q];
      acc[q].x+=hv*wv.x;acc[q].y+=hv*wv.y;acc[q].z+=hv*wv.z;acc[q].w+=hv*wv.w;}
  }
  float ssv=0.f,sdv=0.f;
  #pragma unroll
  for(int q=0;q<8;q++){
    float4 a1=av4[h*8+q],a2=av4[32+h*8+q];
    ssv+=acc[q].x*a1.x+acc[q].y*a1.y+acc[q].z*a1.z+acc[q].w*a1.w;
    sdv+=acc[q].x*a2.x+acc[q].y*a2.y+acc[q].z*a2.z+acc[q].w*a2.w;
  }
  int p=b*4+h;
  float4* o4=(float4*)(hp+((size_t)p*N_+n)*32);
  #pragma unroll
  for(int q=0;q<8;q++) o4[q]=acc[q];
  ss[(size_t)p*N_+n]=ssv; sd[(size_t)p*N_+n]=sdv;
}

// ---------- layer1 projection with inline norm (s via folded w1@a) -----------
__global__ void kproj1(const float* __restrict__ x, const float* __restrict__ stats,
                       const float* __restrict__ w1, const float* __restrict__ asrc,
                       const float* __restrict__ adst, float* __restrict__ hp,
                       float* __restrict__ ss, float* __restrict__ sd){
  __shared__ float4 w4[2048];
  __shared__ float wa[128],wd[128],mean[128],rstd[128];
  int tid=threadIdx.x;
  const float4* wg=(const float4*)w1;
  for(int i=tid;i<2048;i+=256) w4[i]=wg[i];
  int gid=blockIdx.x*256+tid;
  int b=gid>>14;
  if(tid<128){
    float s1a=0.f,s2a=0.f;
    for(int k=0;k<64;k++){float wv=w1[tid*64+k];s1a+=wv*asrc[k];s2a+=wv*adst[k];}
    wa[tid]=s1a;wd[tid]=s2a;
    float s1=stats[(size_t)(b*128+tid)*2+0],s2=stats[(size_t)(b*128+tid)*2+1];
    float mu=s1*(1.0f/N_);
    float var=s2*(1.0f/N_)-mu*mu;
    mean[tid]=mu; rstd[tid]=rsqrtf(var+1e-5f);
  }
  __syncthreads();
  int n=(gid>>2)&4095, q4=gid&3;
  const float4* hr4=(const float4*)(x+((size_t)(b*N_+n))*128);
  float hrow[128];
  #pragma unroll
  for(int q=0;q<32;q++){
    float4 t=hr4[q];
    hrow[4*q+0]=(t.x-mean[4*q+0])*rstd[4*q+0];
    hrow[4*q+1]=(t.y-mean[4*q+1])*rstd[4*q+1];
    hrow[4*q+2]=(t.z-mean[4*q+2])*rstd[4*q+2];
    hrow[4*q+3]=(t.w-mean[4*q+3])*rstd[4*q+3];
  }
  float4 acc[4];
  #pragma unroll
  for(int q=0;q<4;q++) acc[q]=make_float4(0.f,0.f,0.f,0.f);
  #pragma unroll
  for(int d=0;d<128;d++){
    float hv=hrow[d];
    #pragma unroll
    for(int q=0;q<4;q++){float4 wv=w4[d*16+q4*4+q];
      acc[q].x+=hv*wv.x;acc[q].y+=hv*wv.y;acc[q].z+=hv*wv.z;acc[q].w+=hv*wv.w;}
  }
  float4* o4=(float4*)(hp+((size_t)(b*N_+n))*64+q4*16);
  #pragma unroll
  for(int q=0;q<4;q++) o4[q]=acc[q];
  if(q4==0){
    float s1=0.f,s2=0.f;
    #pragma unroll
    for(int d=0;d<128;d++){s1+=hrow[d]*wa[d];s2+=hrow[d]*wd[d];}
    ss[(size_t)b*N_+n]=s1;sd[(size_t)b*N_+n]=s2;
  }
}

// ---------- sort runs of 1024 (packed u64 = key<<32 | orig_idx) --------------
__global__ void __launch_bounds__(256) ksort_runs(const float* __restrict__ sdst,
                                                  unsigned long long* __restrict__ runs){
  __shared__ unsigned long long sm[1024];
  int p=blockIdx.x>>2, run=blockIdx.x&3;
  int tid=threadIdx.x;
  const float* s=sdst+(size_t)p*N_+run*1024;
  for(int l=tid;l<1024;l+=256){
    unsigned key=f2s(s[l]);
    sm[l]=((unsigned long long)key<<32)|(unsigned)(run*1024+l);
  }
  for(unsigned k=2;k<=1024u;k<<=1)
    for(unsigned j=k>>1;j>0;j>>=1){
      __syncthreads();
      for(unsigned t=tid;t<512u;t+=256u){
        unsigned i=((t&~(j-1))<<1)|(t&(j-1));
        unsigned q=i|j;
        bool up=((i&k)==0);
        unsigned long long a=sm[i],b=sm[q];
        if((a>b)==up){sm[i]=b;sm[q]=a;}
      }
    }
  __syncthreads();
  unsigned long long* rg=runs+(size_t)p*N_+run*1024;
  for(int l=tid;l<1024;l+=256) rg[l]=sm[l];
}

// ---------- merge 4 sorted runs by rank (binary search in LDS) ---------------
__global__ void __launch_bounds__(1024) kmerge(const unsigned long long* __restrict__ runs,
    float* __restrict__ sv, unsigned* __restrict__ perm,
    float* __restrict__ eP, float* __restrict__ eN){
  __shared__ unsigned long long sm[4096];
  int p=blockIdx.x>>2, cg=blockIdx.x&3;
  int tid=threadIdx.x;
  const unsigned long long* rg=runs+(size_t)p*N_;
  for(int l=tid;l<4096;l+=1024) sm[l]=rg[l];
  __syncthreads();
  unsigned long long e=sm[cg*1024+tid];
  int rank=tid;
  #pragma unroll
  for(int o=0;o<4;o++){
    if(o==cg) continue;
    const unsigned long long* base=sm+o*1024;
    int lo=0,hi=1024;
    while(lo<hi){int mid=(lo+hi)>>1; if(base[mid]<e) lo=mid+1; else hi=mid;}
    rank+=lo;
  }
  unsigned long long mk=sm[1023];
  if(sm[2047]>mk) mk=sm[2047];
  if(sm[3071]>mk) mk=sm[3071];
  if(sm[4095]>mk) mk=sm[4095];
  float m=s2f((unsigned)(mk>>32));
  float v=s2f((unsigned)(e>>32));
  size_t o=(size_t)p*N_+rank;
  sv[o]=v;
  perm[o]=(unsigned)(e&0xffffffffu);
  eP[o]=expf(v-m);
  eN[o]=expf(0.2f*(v-m));
}

// ---------- chunk sums (32-rank chunks) + in-kernel exclusive scan -----------
template<int D,int DPAD>
__global__ void __launch_bounds__(1024) kchunks(const unsigned* __restrict__ perm,
    const float* __restrict__ eP, const float* __restrict__ eN,
    const float* __restrict__ hp, float* __restrict__ bP, float* __restrict__ bN){
  int p=blockIdx.x, tid=threadIdx.x;
  const unsigned* pm=perm+(size_t)p*N_;
  const float* ePb=eP+(size_t)p*N_;
  const float* eNb=eN+(size_t)p*N_;
  const float* hb=hp+(size_t)p*N_*D;
  for(int tt=tid;tt<128*(D+1);tt+=1024){
    int c=tt/(D+1),kk=tt%(D+1);
    float sp=0.f,sn=0.f;
    for(int q=0;q<32;q++){
      int r=c*32+q;
      float hv=(kk<D)?hb[(size_t)pm[r]*D+kk]:1.0f;
      sp+=ePb[r]*hv;sn+=eNb[r]*hv;
    }
    bP[((size_t)p*129+c)*DPAD+kk]=sp;
    bN[((size_t)p*129+c)*DPAD+kk]=sn;
  }
  __syncthreads();
  if(tid<D+1){
    float rp=0.f,rn=0.f;
    for(int c=0;c<128;c++){
      size_t idx=((size_t)p*129+c)*DPAD+tid;
      float tpv=bP[idx],tnv=bN[idx];
      bP[idx]=rp;bN[idx]=rn;
      rp+=tpv;rn+=tnv;
    }
    bP[((size_t)p*129+128)*DPAD+tid]=rp;
    bN[((size_t)p*129+128)*DPAD+tid]=rn;
  }
}

// ---------- layer0 row eval: bases + residual, +bias, ELU, head-concat -------
__global__ void keval0(const float* __restrict__ ss, const float* __restrict__ sv,
                       const float* __restrict__ bP, const float* __restrict__ bN,
                       const float* __restrict__ hp, const unsigned* __restrict__ perm,
                       const float* __restrict__ eP, const float* __restrict__ eN,
                       const float* __restrict__ bias, float* __restrict__ out){
  int gid=blockIdx.x*256+threadIdx.x;
  int p=gid>>12, i=gid&4095;
  int b=p>>2,h=p&3;
  const float* svp=sv+(size_t)p*N_;
  float ssrc=ss[(size_t)p*N_+i];
  float m=svp[4095];
  float xx=ssrc+m;
  float M=xx>0.f?xx:0.2f*xx;
  float fpos=expf(xx-M),fneg=expf(0.2f*xx-M);
  float th=-ssrc;
  int lo=0,hi=4096;
  while(lo<hi){int mid=(lo+hi)>>1; if(svp[mid]<=th) lo=mid+1; else hi=mid;}
  int c=lo>>5;
  float4 aP[8],aN[8];
  #pragma unroll
  for(int q=0;q<8;q++){aP[q]=make_float4(0.f,0.f,0.f,0.f);aN[q]=make_float4(0.f,0.f,0.f,0.f);}
  float aPd=0.f,aNd=0.f;
  for(int r=c*32;r<lo;r++){
    unsigned pr=perm[(size_t)p*N_+r];
    float ep=eP[(size_t)p*N_+r],en=eN[(size_t)p*N_+r];
    const float4* hr=(const float4*)(hp+((size_t)p*N_+pr)*32);
    aPd+=ep;aNd+=en;
    #pragma unroll
    for(int q=0;q<8;q++){
      float4 hv=hr[q];
      aP[q].x+=ep*hv.x;aP[q].y+=ep*hv.y;aP[q].z+=ep*hv.z;aP[q].w+=ep*hv.w;
      aN[q].x+=en*hv.x;aN[q].y+=en*hv.y;aN[q].z+=en*hv.z;aN[q].w+=en*hv.w;
    }
  }
  const float* bp=bP+((size_t)p*129+c)*36;
  const float* bn=bN+((size_t)p*129+c)*36;
  const float* tp=bP+((size_t)p*129+128)*36;
  float denom=fpos*(tp[32]-(bp[32]+aPd))+fneg*(bn[32]+aNd);
  float inv=1.0f/denom;
  float* op=out+((size_t)(b*N_+i))*128+h*32;
  #pragma unroll
  for(int q=0;q<8;q++){
    float4 B4=((const float4*)bp)[q],Bn4=((const float4*)bn)[q],T4=((const float4*)tp)[q];
    float4 r;
    r.x=(fpos*(T4.x-(B4.x+aP[q].x))+fneg*(Bn4.x+aN[q].x))*inv+bias[4*q+0];
    r.y=(fpos*(T4.y-(B4.y+aP[q].y))+fneg*(Bn4.y+aN[q].y))*inv+bias[4*q+1];
    r.z=(fpos*(T4.z-(B4.z+aP[q].z))+fneg*(Bn4.z+aN[q].z))*inv+bias[4*q+2];
    r.w=(fpos*(T4.w-(B4.w+aP[q].w))+fneg*(Bn4.w+aN[q].w))*inv+bias[4*q+3];
    r.x=r.x>0.f?r.x:expm1f(r.x);
    r.y=r.y>0.f?r.y:expm1f(r.y);
    r.z=r.z>0.f?r.z:expm1f(r.z);
    r.w=r.w>0.f?r.w:expm1f(r.w);
    ((float4*)op)[q]=r;
  }
}

// ---------- layer1 row eval (split channels in half per thread) --------------
__global__ void keval1(const float* __restrict__ ss, const float* __restrict__ sv,
                       const float* __restrict__ bP, const float* __restrict__ bN,
                       const float* __restrict__ hp, const unsigned* __restrict__ perm,
                       const float* __restrict__ eP, const float* __restrict__ eN,
                       const float* __restrict__ bias, float* __restrict__ out){
  int gid=blockIdx.x*256+threadIdx.x;
  int kb=gid&1, i=(gid>>1)&4095, p=gid>>13;
  const float* svp=sv+(size_t)p*N_;
  float ssrc=ss[(size_t)p*N_+i];
  float m=svp[4095];
  float xx=ssrc+m;
  float M=xx>0.f?xx:0.2f*xx;
  float fpos=expf(xx-M),fneg=expf(0.2f*xx-M);
  float th=-ssrc;
  int lo=0,hi=4096;
  while(lo<hi){int mid=(lo+hi)>>1; if(svp[mid]<=th) lo=mid+1; else hi=mid;}
  int c=lo>>5;
  float4 aP[8],aN[8];
  #pragma unroll
  for(int q=0;q<8;q++){aP[q]=make_float4(0.f,0.f,0.f,0.f);aN[q]=make_float4(0.f,0.f,0.f,0.f);}
  float aPd=0.f,aNd=0.f;
  for(int r=c*32;r<lo;r++){
    unsigned pr=perm[(size_t)p*N_+r];
    float ep=eP[(size_t)p*N_+r],en=eN[(size_t)p*N_+r];
    const float4* hr=(const float4*)(hp+((size_t)p*N_+pr)*64+kb*32);
    aPd+=ep;aNd+=en;
    #pragma unroll
    for(int q=0;q<8;q++){
      float4 hv=hr[q];
      aP[q].x+=ep*hv.x;aP[q].y+=ep*hv.y;aP[q].z+=ep*hv.z;aP[q].w+=ep*hv.w;
      aN[q].x+=en*hv.x;aN[q].y+=en*hv.y;aN[q].z+=en*hv.z;aN[q].w+=en*hv.w;
    }
  }
  const float* bpr=bP+((size_t)p*129+c)*68;
  const float* bnr=bN+((size_t)p*129+c)*68;
  const float* tpr=bP+((size_t)p*129+128)*68;
  float denom=fpos*(tpr[64]-(bpr[64]+aPd))+fneg*(bnr[64]+aNd);
  float inv=1.0f/denom;
  const float* bp=bpr+kb*32;
  const float* bn=bnr+kb*32;
  const float* tp=tpr+kb*32;
  const float* bi=bias+kb*32;
  float* op=out+((size_t)p*N_+i)*64+kb*32;
  #pragma unroll
  for(int q=0;q<8;q++){
    float4 B4=((const float4*)bp)[q],Bn4=((const float4*)bn)[q],T4=((const float4*)tp)[q];
    float4 r;
    r.x=(fpos*(T4.x-(B4.x+aP[q].x))+fneg*(Bn4.x+aN[q].x))*inv+bi[4*q+0];
    r.y=(fpos*(T4.y-(B4.y+aP[q].y))+fneg*(Bn4.y+aN[q].y))*inv+bi[4*q+1];
    r.z=(fpos*(T4.z-(B4.z+aP[q].z))+fneg*(Bn4.z+aN[q].z))*inv+bi[4*q+2];
    r.w=(fpos*(T4.w-(B4.w+aP[q].w))+fneg*(Bn4.w+aN[q].w))*inv+bi[4*q+3];
    ((float4*)op)[q]=r;
  }
}

extern "C" void kernel_launch(void* const* d_in, const int* in_sizes, int n_in,
                              void* d_out, int out_size, void* d_ws, size_t ws_size,
                              hipStream_t stream) {
  const float* x  =(const float*)d_in[0];
  const float* w0 =(const float*)d_in[1];
  const float* as0=(const float*)d_in[2];
  const float* ad0=(const float*)d_in[3];
  const float* b0 =(const float*)d_in[4];
  const float* w1 =(const float*)d_in[5];
  const float* as1=(const float*)d_in[6];
  const float* ad1=(const float*)d_in[7];
  const float* b1 =(const float*)d_in[8];
  float* ws=(float*)d_ws;
  float* out=(float*)d_out;

  float* st0 = ws+OFF_STATS0;
  float* st1 = ws+OFF_STATS1;
  float* hp0 = ws+OFF_HP0;
  float* ss0 = ws+OFF_SS0;  float* sd0 = ws+OFF_SD0;
  unsigned long long* runs0=(unsigned long long*)(ws+OFF_RUNS0);
  float* sv0 = ws+OFF_SV0;
  unsigned* pm0=(unsigned*)(ws+OFF_PM0);
  float* eP0 = ws+OFF_EP0;  float* eN0 = ws+OFF_EN0;
  float* bP0 = ws+OFF_BP0;  float* bN0 = ws+OFF_BN0;
  float* elu = ws+OFF_ELU;
  float* hp1 = ws+OFF_HP1;
  float* ss1 = ws+OFF_SS1;  float* sd1 = ws+OFF_SD1;
  unsigned long long* runs1=(unsigned long long*)(ws+OFF_RUNS1);
  float* sv1 = ws+OFF_SV1;
  unsigned* pm1=(unsigned*)(ws+OFF_PM1);
  float* eP1 = ws+OFF_EP1;  float* eN1 = ws+OFF_EN1;
  float* bP1 = ws+OFF_BP1;  float* bN1 = ws+OFF_BN1;

  hipMemsetAsync(d_ws, 0, 1536*sizeof(float), stream);

  // ---- layer 0 ----
  kstats<64><<<128,256,0,stream>>>(x,st0);
  kproj0<<<256,256,0,stream>>>(x,st0,w0,as0,ad0,hp0,ss0,sd0);
  ksort_runs<<<64,256,0,stream>>>(sd0,runs0);
  kmerge<<<64,1024,0,stream>>>(runs0,sv0,pm0,eP0,eN0);
  kchunks<32,36><<<16,1024,0,stream>>>(pm0,eP0,eN0,hp0,bP0,bN0);
  keval0<<<256,256,0,stream>>>(ss0,sv0,bP0,bN0,hp0,pm0,eP0,eN0,b0,elu);
  // ---- layer 1 ----
  kstats<128><<<128,256,0,stream>>>(elu,st1);
  kproj1<<<256,256,0,stream>>>(elu,st1,w1,as1,ad1,hp1,ss1,sd1);
  ksort_runs<<<16,256,0,stream>>>(sd1,runs1);
  kmerge<<<16,1024,0,stream>>>(runs1,sv1,pm1,eP1,eN1);
  kchunks<64,68><<<4,1024,0,stream>>>(pm1,eP1,eN1,hp1,bP1,bN1);
  keval1<<<128,256,0,stream>>>(ss1,sv1,bP1,bN1,hp1,pm1,eP1,eN1,b1,out);
}

// Round 3
// 339.357 us; speedup vs baseline: 1.4773x; 1.4023x over previous
//
#include <hip/hip_runtime.h>
#include <math.h>

#define N_ 4096

// ---------------- workspace float offsets -----------------------------------
static constexpr size_t OFF_STATS0 = 0;        // [4][64][2]
static constexpr size_t OFF_STATS1 = 512;      // [4][128][2] (memset 1536 floats)
static constexpr size_t OFF_HP0    = 2048;     // [16][4096][32]
static constexpr size_t OFF_SS0    = 2099200;
static constexpr size_t OFF_SD0    = 2164736;
static constexpr size_t OFF_RUNS0  = 2230272;  // u64[16][4096]
static constexpr size_t OFF_SV0    = 2361344;
static constexpr size_t OFF_PM0    = 2426880;
static constexpr size_t OFF_EP0    = 2492416;
static constexpr size_t OFF_EN0    = 2557952;
static constexpr size_t OFF_RAWP0  = 2623488;  // [16][128][36]
static constexpr size_t OFF_RAWN0  = 2697216;
static constexpr size_t OFF_BP0    = 2770944;  // [16][129][36]
static constexpr size_t OFF_BN0    = 2845248;
static constexpr size_t OFF_ELU    = 2919552;  // [4][4096][128]
static constexpr size_t OFF_HP1    = 5016704;  // [4][4096][64]
static constexpr size_t OFF_SS1    = 6065280;
static constexpr size_t OFF_SD1    = 6081664;
static constexpr size_t OFF_RUNS1  = 6098048;  // u64[4][4096]
static constexpr size_t OFF_SV1    = 6130816;
static constexpr size_t OFF_PM1    = 6147200;
static constexpr size_t OFF_EP1    = 6163584;
static constexpr size_t OFF_EN1    = 6179968;
static constexpr size_t OFF_RAWP1  = 6196352;  // [4][128][68]
static constexpr size_t OFF_RAWN1  = 6231168;
static constexpr size_t OFF_BP1    = 6265984;  // [4][129][68]
static constexpr size_t OFF_BN1    = 6301072;  // end 6336160 floats ~= 25.3 MB

__device__ __forceinline__ unsigned f2s(float f){
  unsigned u=__float_as_uint(f);
  return u^((u&0x80000000u)?0xFFFFFFFFu:0x80000000u);
}
__device__ __forceinline__ float s2f(unsigned s){
  unsigned u=(s&0x80000000u)?(s^0x80000000u):~s;
  return __uint_as_float(u);
}

// ---------- partial stats (coalesced) + atomic accumulate --------------------
template<int C>
__global__ void kstats(const float* __restrict__ x, float* __restrict__ stats){
  int blk=blockIdx.x; int b=blk>>5, seg=blk&31;
  int tid=threadIdx.x;
  const int RPT=256/C;
  const int IT=128/RPT;
  int c=tid%C, rl=tid/C;
  const float* xb=x+(size_t)b*N_*C;
  float s1=0.f,s2=0.f;
  int r0=seg*128+rl;
  for(int i=0;i<IT;i++){
    float v=xb[(size_t)(r0+i*RPT)*C+c];
    s1+=v;s2+=v*v;
  }
  __shared__ float sh1[256],sh2[256];
  sh1[tid]=s1;sh2[tid]=s2;__syncthreads();
  if(tid<C){
    float a1=0.f,a2=0.f;
    for(int g=0;g<RPT;g++){a1+=sh1[g*C+tid];a2+=sh2[g*C+tid];}
    atomicAdd(&stats[(size_t)(b*C+tid)*2+0],a1);
    atomicAdd(&stats[(size_t)(b*C+tid)*2+1],a2);
  }
}

// ---------- layer0 projection with inline instance-norm ----------------------
__global__ void kproj0(const float* __restrict__ x, const float* __restrict__ stats,
                       const float* __restrict__ w0, const float* __restrict__ asrc,
                       const float* __restrict__ adst, float* __restrict__ hp,
                       float* __restrict__ ss, float* __restrict__ sd){
  __shared__ float4 w4[2048];
  __shared__ float4 av4[64];
  __shared__ float mean[64],rstd[64];
  int tid=threadIdx.x;
  const float4* wg=(const float4*)w0;
  for(int i=tid;i<2048;i+=256) w4[i]=wg[i];
  if(tid<32) av4[tid]=((const float4*)asrc)[tid];
  else if(tid<64) av4[tid]=((const float4*)adst)[tid-32];
  int gid=blockIdx.x*256+tid;
  int b=gid>>14;
  if(tid<64){
    float s1=stats[(size_t)(b*64+tid)*2+0],s2=stats[(size_t)(b*64+tid)*2+1];
    float mu=s1*(1.0f/N_);
    float var=s2*(1.0f/N_)-mu*mu;
    mean[tid]=mu; rstd[tid]=rsqrtf(var+1e-5f);
  }
  __syncthreads();
  int n=(gid>>2)&4095, h=gid&3;
  const float4* hr4=(const float4*)(x+((size_t)(b*N_+n))*64);
  float hrow[64];
  #pragma unroll
  for(int q=0;q<16;q++){
    float4 t=hr4[q];
    hrow[4*q+0]=(t.x-mean[4*q+0])*rstd[4*q+0];
    hrow[4*q+1]=(t.y-mean[4*q+1])*rstd[4*q+1];
    hrow[4*q+2]=(t.z-mean[4*q+2])*rstd[4*q+2];
    hrow[4*q+3]=(t.w-mean[4*q+3])*rstd[4*q+3];
  }
  float4 acc[8];
  #pragma unroll
  for(int q=0;q<8;q++) acc[q]=make_float4(0.f,0.f,0.f,0.f);
  #pragma unroll
  for(int d=0;d<64;d++){
    float hv=hrow[d];
    #pragma unroll
    for(int q=0;q<8;q++){float4 wv=w4[(h*64+d)*8+q];
      acc[q].x+=hv*wv.x;acc[q].y+=hv*wv.y;acc[q].z+=hv*wv.z;acc[q].w+=hv*wv.w;}
  }
  float ssv=0.f,sdv=0.f;
  #pragma unroll
  for(int q=0;q<8;q++){
    float4 a1=av4[h*8+q],a2=av4[32+h*8+q];
    ssv+=acc[q].x*a1.x+acc[q].y*a1.y+acc[q].z*a1.z+acc[q].w*a1.w;
    sdv+=acc[q].x*a2.x+acc[q].y*a2.y+acc[q].z*a2.z+acc[q].w*a2.w;
  }
  int p=b*4+h;
  float4* o4=(float4*)(hp+((size_t)p*N_+n)*32);
  #pragma unroll
  for(int q=0;q<8;q++) o4[q]=acc[q];
  ss[(size_t)p*N_+n]=ssv; sd[(size_t)p*N_+n]=sdv;
}

// ---------- layer1 projection with inline norm (s via folded w1@a) -----------
__global__ void kproj1(const float* __restrict__ x, const float* __restrict__ stats,
                       const float* __restrict__ w1, const float* __restrict__ asrc,
                       const float* __restrict__ adst, float* __restrict__ hp,
                       float* __restrict__ ss, float* __restrict__ sd){
  __shared__ float4 w4[2048];
  __shared__ float wa[128],wd[128],mean[128],rstd[128];
  int tid=threadIdx.x;
  const float4* wg=(const float4*)w1;
  for(int i=tid;i<2048;i+=256) w4[i]=wg[i];
  int gid=blockIdx.x*256+tid;
  int b=gid>>14;
  if(tid<128){
    float s1a=0.f,s2a=0.f;
    for(int k=0;k<64;k++){float wv=w1[tid*64+k];s1a+=wv*asrc[k];s2a+=wv*adst[k];}
    wa[tid]=s1a;wd[tid]=s2a;
    float s1=stats[(size_t)(b*128+tid)*2+0],s2=stats[(size_t)(b*128+tid)*2+1];
    float mu=s1*(1.0f/N_);
    float var=s2*(1.0f/N_)-mu*mu;
    mean[tid]=mu; rstd[tid]=rsqrtf(var+1e-5f);
  }
  __syncthreads();
  int n=(gid>>2)&4095, q4=gid&3;
  const float4* hr4=(const float4*)(x+((size_t)(b*N_+n))*128);
  float hrow[128];
  #pragma unroll
  for(int q=0;q<32;q++){
    float4 t=hr4[q];
    hrow[4*q+0]=(t.x-mean[4*q+0])*rstd[4*q+0];
    hrow[4*q+1]=(t.y-mean[4*q+1])*rstd[4*q+1];
    hrow[4*q+2]=(t.z-mean[4*q+2])*rstd[4*q+2];
    hrow[4*q+3]=(t.w-mean[4*q+3])*rstd[4*q+3];
  }
  float4 acc[4];
  #pragma unroll
  for(int q=0;q<4;q++) acc[q]=make_float4(0.f,0.f,0.f,0.f);
  #pragma unroll
  for(int d=0;d<128;d++){
    float hv=hrow[d];
    #pragma unroll
    for(int q=0;q<4;q++){float4 wv=w4[d*16+q4*4+q];
      acc[q].x+=hv*wv.x;acc[q].y+=hv*wv.y;acc[q].z+=hv*wv.z;acc[q].w+=hv*wv.w;}
  }
  float4* o4=(float4*)(hp+((size_t)(b*N_+n))*64+q4*16);
  #pragma unroll
  for(int q=0;q<4;q++) o4[q]=acc[q];
  if(q4==0){
    float s1=0.f,s2=0.f;
    #pragma unroll
    for(int d=0;d<128;d++){s1+=hrow[d]*wa[d];s2+=hrow[d]*wd[d];}
    ss[(size_t)b*N_+n]=s1;sd[(size_t)b*N_+n]=s2;
  }
}

// ---------- sort runs of 1024 (packed u64 = key<<32 | orig_idx) --------------
__global__ void __launch_bounds__(256) ksort_runs(const float* __restrict__ sdst,
                                                  unsigned long long* __restrict__ runs){
  __shared__ unsigned long long sm[1024];
  int p=blockIdx.x>>2, run=blockIdx.x&3;
  int tid=threadIdx.x;
  const float* s=sdst+(size_t)p*N_+run*1024;
  for(int l=tid;l<1024;l+=256){
    unsigned key=f2s(s[l]);
    sm[l]=((unsigned long long)key<<32)|(unsigned)(run*1024+l);
  }
  for(unsigned k=2;k<=1024u;k<<=1)
    for(unsigned j=k>>1;j>0;j>>=1){
      __syncthreads();
      for(unsigned t=tid;t<512u;t+=256u){
        unsigned i=((t&~(j-1))<<1)|(t&(j-1));
        unsigned q=i|j;
        bool up=((i&k)==0);
        unsigned long long a=sm[i],b=sm[q];
        if((a>b)==up){sm[i]=b;sm[q]=a;}
      }
    }
  __syncthreads();
  unsigned long long* rg=runs+(size_t)p*N_+run*1024;
  for(int l=tid;l<1024;l+=256) rg[l]=sm[l];
}

// ---------- merge 4 sorted runs by rank (binary search in LDS) ---------------
__global__ void __launch_bounds__(1024) kmerge(const unsigned long long* __restrict__ runs,
    float* __restrict__ sv, unsigned* __restrict__ perm,
    float* __restrict__ eP, float* __restrict__ eN){
  __shared__ unsigned long long sm[4096];
  int p=blockIdx.x>>2, cg=blockIdx.x&3;
  int tid=threadIdx.x;
  const unsigned long long* rg=runs+(size_t)p*N_;
  for(int l=tid;l<4096;l+=1024) sm[l]=rg[l];
  __syncthreads();
  unsigned long long e=sm[cg*1024+tid];
  int rank=tid;
  #pragma unroll
  for(int o=0;o<4;o++){
    if(o==cg) continue;
    const unsigned long long* base=sm+o*1024;
    int lo=0,hi=1024;
    while(lo<hi){int mid=(lo+hi)>>1; if(base[mid]<e) lo=mid+1; else hi=mid;}
    rank+=lo;
  }
  unsigned long long mk=sm[1023];
  if(sm[2047]>mk) mk=sm[2047];
  if(sm[3071]>mk) mk=sm[3071];
  if(sm[4095]>mk) mk=sm[4095];
  float m=s2f((unsigned)(mk>>32));
  float v=s2f((unsigned)(e>>32));
  size_t o=(size_t)p*N_+rank;
  sv[o]=v;
  perm[o]=(unsigned)(e&0xffffffffu);
  eP[o]=expf(v-m);
  eN[o]=expf(0.2f*(v-m));
}

// ---------- chunk sums (32-rank chunks), occupancy-spread --------------------
template<int D,int DPAD,int CPB>
__global__ void __launch_bounds__(256) kchunksA(const unsigned* __restrict__ perm,
    const float* __restrict__ eP, const float* __restrict__ eN,
    const float* __restrict__ hp, float* __restrict__ rawP, float* __restrict__ rawN){
  const int G=128/CPB;
  int p=blockIdx.x/G, cg=blockIdx.x%G;
  int tid=threadIdx.x;
  __shared__ unsigned pmL[CPB*32];
  __shared__ float ePL[CPB*32],eNL[CPB*32];
  int r0=cg*CPB*32;
  for(int i=tid;i<CPB*32;i+=256){
    pmL[i]=perm[(size_t)p*N_+r0+i];
    ePL[i]=eP[(size_t)p*N_+r0+i];
    eNL[i]=eN[(size_t)p*N_+r0+i];
  }
  __syncthreads();
  const float* hb=hp+(size_t)p*N_*D;
  for(int tt=tid;tt<CPB*(D+1);tt+=256){
    int cl=tt/(D+1), kk=tt%(D+1);
    float sp=0.f,sn=0.f;
    #pragma unroll 4
    for(int q=0;q<32;q++){
      int rl=cl*32+q;
      float hv=(kk<D)?hb[(size_t)pmL[rl]*D+kk]:1.0f;
      sp+=ePL[rl]*hv; sn+=eNL[rl]*hv;
    }
    int c=cg*CPB+cl;
    rawP[((size_t)p*128+c)*DPAD+kk]=sp;
    rawN[((size_t)p*128+c)*DPAD+kk]=sn;
  }
}

// ---------- exclusive scan over 128 chunks, entirely in LDS ------------------
template<int D,int DPAD>
__global__ void __launch_bounds__(256) kscan(const float* __restrict__ rawP,
    const float* __restrict__ rawN, float* __restrict__ bP, float* __restrict__ bN){
  extern __shared__ float sm[];
  float* smP=sm;
  float* smN=sm+128*(D+1);
  int p=blockIdx.x, tid=threadIdx.x;
  for(int i=tid;i<128*(D+1);i+=256){
    int c=i/(D+1), kk=i%(D+1);
    smP[i]=rawP[((size_t)p*128+c)*DPAD+kk];
    smN[i]=rawN[((size_t)p*128+c)*DPAD+kk];
  }
  __syncthreads();
  if(tid<2*(D+1)){
    int kk=tid>>1;
    const float* s=(tid&1)?smN:smP;
    float* g=(tid&1)?bN:bP;
    float r=0.f;
    for(int c=0;c<128;c++){
      g[((size_t)p*129+c)*DPAD+kk]=r;
      r+=s[c*(D+1)+kk];
    }
    g[((size_t)p*129+128)*DPAD+kk]=r;
  }
}

// ---------- layer0 row eval: bases + residual, +bias, ELU, head-concat -------
__global__ void keval0(const float* __restrict__ ss, const float* __restrict__ sv,
                       const float* __restrict__ bP, const float* __restrict__ bN,
                       const float* __restrict__ hp, const unsigned* __restrict__ perm,
                       const float* __restrict__ eP, const float* __restrict__ eN,
                       const float* __restrict__ bias, float* __restrict__ out){
  int gid=blockIdx.x*256+threadIdx.x;
  int p=gid>>12, i=gid&4095;
  int b=p>>2,h=p&3;
  const float* svp=sv+(size_t)p*N_;
  float ssrc=ss[(size_t)p*N_+i];
  float m=svp[4095];
  float xx=ssrc+m;
  float M=xx>0.f?xx:0.2f*xx;
  float fpos=expf(xx-M),fneg=expf(0.2f*xx-M);
  float th=-ssrc;
  int lo=0,hi=4096;
  while(lo<hi){int mid=(lo+hi)>>1; if(svp[mid]<=th) lo=mid+1; else hi=mid;}
  int c=lo>>5;
  float4 aP[8],aN[8];
  #pragma unroll
  for(int q=0;q<8;q++){aP[q]=make_float4(0.f,0.f,0.f,0.f);aN[q]=make_float4(0.f,0.f,0.f,0.f);}
  float aPd=0.f,aNd=0.f;
  for(int r=c*32;r<lo;r++){
    unsigned pr=perm[(size_t)p*N_+r];
    float ep=eP[(size_t)p*N_+r],en=eN[(size_t)p*N_+r];
    const float4* hr=(const float4*)(hp+((size_t)p*N_+pr)*32);
    aPd+=ep;aNd+=en;
    #pragma unroll
    for(int q=0;q<8;q++){
      float4 hv=hr[q];
      aP[q].x+=ep*hv.x;aP[q].y+=ep*hv.y;aP[q].z+=ep*hv.z;aP[q].w+=ep*hv.w;
      aN[q].x+=en*hv.x;aN[q].y+=en*hv.y;aN[q].z+=en*hv.z;aN[q].w+=en*hv.w;
    }
  }
  const float* bp=bP+((size_t)p*129+c)*36;
  const float* bn=bN+((size_t)p*129+c)*36;
  const float* tp=bP+((size_t)p*129+128)*36;
  float denom=fpos*(tp[32]-(bp[32]+aPd))+fneg*(bn[32]+aNd);
  float inv=1.0f/denom;
  float* op=out+((size_t)(b*N_+i))*128+h*32;
  #pragma unroll
  for(int q=0;q<8;q++){
    float4 B4=((const float4*)bp)[q],Bn4=((const float4*)bn)[q],T4=((const float4*)tp)[q];
    float4 r;
    r.x=(fpos*(T4.x-(B4.x+aP[q].x))+fneg*(Bn4.x+aN[q].x))*inv+bias[4*q+0];
    r.y=(fpos*(T4.y-(B4.y+aP[q].y))+fneg*(Bn4.y+aN[q].y))*inv+bias[4*q+1];
    r.z=(fpos*(T4.z-(B4.z+aP[q].z))+fneg*(Bn4.z+aN[q].z))*inv+bias[4*q+2];
    r.w=(fpos*(T4.w-(B4.w+aP[q].w))+fneg*(Bn4.w+aN[q].w))*inv+bias[4*q+3];
    r.x=r.x>0.f?r.x:expm1f(r.x);
    r.y=r.y>0.f?r.y:expm1f(r.y);
    r.z=r.z>0.f?r.z:expm1f(r.z);
    r.w=r.w>0.f?r.w:expm1f(r.w);
    ((float4*)op)[q]=r;
  }
}

// ---------- layer1 row eval (split channels in half per thread) --------------
__global__ void keval1(const float* __restrict__ ss, const float* __restrict__ sv,
                       const float* __restrict__ bP, const float* __restrict__ bN,
                       const float* __restrict__ hp, const unsigned* __restrict__ perm,
                       const float* __restrict__ eP, const float* __restrict__ eN,
                       const float* __restrict__ bias, float* __restrict__ out){
  int gid=blockIdx.x*256+threadIdx.x;
  int kb=gid&1, i=(gid>>1)&4095, p=gid>>13;
  const float* svp=sv+(size_t)p*N_;
  float ssrc=ss[(size_t)p*N_+i];
  float m=svp[4095];
  float xx=ssrc+m;
  float M=xx>0.f?xx:0.2f*xx;
  float fpos=expf(xx-M),fneg=expf(0.2f*xx-M);
  float th=-ssrc;
  int lo=0,hi=4096;
  while(lo<hi){int mid=(lo+hi)>>1; if(svp[mid]<=th) lo=mid+1; else hi=mid;}
  int c=lo>>5;
  float4 aP[8],aN[8];
  #pragma unroll
  for(int q=0;q<8;q++){aP[q]=make_float4(0.f,0.f,0.f,0.f);aN[q]=make_float4(0.f,0.f,0.f,0.f);}
  float aPd=0.f,aNd=0.f;
  for(int r=c*32;r<lo;r++){
    unsigned pr=perm[(size_t)p*N_+r];
    float ep=eP[(size_t)p*N_+r],en=eN[(size_t)p*N_+r];
    const float4* hr=(const float4*)(hp+((size_t)p*N_+pr)*64+kb*32);
    aPd+=ep;aNd+=en;
    #pragma unroll
    for(int q=0;q<8;q++){
      float4 hv=hr[q];
      aP[q].x+=ep*hv.x;aP[q].y+=ep*hv.y;aP[q].z+=ep*hv.z;aP[q].w+=ep*hv.w;
      aN[q].x+=en*hv.x;aN[q].y+=en*hv.y;aN[q].z+=en*hv.z;aN[q].w+=en*hv.w;
    }
  }
  const float* bpr=bP+((size_t)p*129+c)*68;
  const float* bnr=bN+((size_t)p*129+c)*68;
  const float* tpr=bP+((size_t)p*129+128)*68;
  float denom=fpos*(tpr[64]-(bpr[64]+aPd))+fneg*(bnr[64]+aNd);
  float inv=1.0f/denom;
  const float* bp=bpr+kb*32;
  const float* bn=bnr+kb*32;
  const float* tp=tpr+kb*32;
  const float* bi=bias+kb*32;
  float* op=out+((size_t)p*N_+i)*64+kb*32;
  #pragma unroll
  for(int q=0;q<8;q++){
    float4 B4=((const float4*)bp)[q],Bn4=((const float4*)bn)[q],T4=((const float4*)tp)[q];
    float4 r;
    r.x=(fpos*(T4.x-(B4.x+aP[q].x))+fneg*(Bn4.x+aN[q].x))*inv+bi[4*q+0];
    r.y=(fpos*(T4.y-(B4.y+aP[q].y))+fneg*(Bn4.y+aN[q].y))*inv+bi[4*q+1];
    r.z=(fpos*(T4.z-(B4.z+aP[q].z))+fneg*(Bn4.z+aN[q].z))*inv+bi[4*q+2];
    r.w=(fpos*(T4.w-(B4.w+aP[q].w))+fneg*(Bn4.w+aN[q].w))*inv+bi[4*q+3];
    ((float4*)op)[q]=r;
  }
}

extern "C" void kernel_launch(void* const* d_in, const int* in_sizes, int n_in,
                              void* d_out, int out_size, void* d_ws, size_t ws_size,
                              hipStream_t stream) {
  const float* x  =(const float*)d_in[0];
  const float* w0 =(const float*)d_in[1];
  const float* as0=(const float*)d_in[2];
  const float* ad0=(const float*)d_in[3];
  const float* b0 =(const float*)d_in[4];
  const float* w1 =(const float*)d_in[5];
  const float* as1=(const float*)d_in[6];
  const float* ad1=(const float*)d_in[7];
  const float* b1 =(const float*)d_in[8];
  float* ws=(float*)d_ws;
  float* out=(float*)d_out;

  float* st0 = ws+OFF_STATS0;
  float* st1 = ws+OFF_STATS1;
  float* hp0 = ws+OFF_HP0;
  float* ss0 = ws+OFF_SS0;  float* sd0 = ws+OFF_SD0;
  unsigned long long* runs0=(unsigned long long*)(ws+OFF_RUNS0);
  float* sv0 = ws+OFF_SV0;
  unsigned* pm0=(unsigned*)(ws+OFF_PM0);
  float* eP0 = ws+OFF_EP0;  float* eN0 = ws+OFF_EN0;
  float* rP0 = ws+OFF_RAWP0; float* rN0 = ws+OFF_RAWN0;
  float* bP0 = ws+OFF_BP0;  float* bN0 = ws+OFF_BN0;
  float* elu = ws+OFF_ELU;
  float* hp1 = ws+OFF_HP1;
  float* ss1 = ws+OFF_SS1;  float* sd1 = ws+OFF_SD1;
  unsigned long long* runs1=(unsigned long long*)(ws+OFF_RUNS1);
  float* sv1 = ws+OFF_SV1;
  unsigned* pm1=(unsigned*)(ws+OFF_PM1);
  float* eP1 = ws+OFF_EP1;  float* eN1 = ws+OFF_EN1;
  float* rP1 = ws+OFF_RAWP1; float* rN1 = ws+OFF_RAWN1;
  float* bP1 = ws+OFF_BP1;  float* bN1 = ws+OFF_BN1;

  hipMemsetAsync(d_ws, 0, 1536*sizeof(float), stream);

  // ---- layer 0 ----
  kstats<64><<<128,256,0,stream>>>(x,st0);
  kproj0<<<256,256,0,stream>>>(x,st0,w0,as0,ad0,hp0,ss0,sd0);
  ksort_runs<<<64,256,0,stream>>>(sd0,runs0);
  kmerge<<<64,1024,0,stream>>>(runs0,sv0,pm0,eP0,eN0);
  kchunksA<32,36,8><<<256,256,0,stream>>>(pm0,eP0,eN0,hp0,rP0,rN0);
  kscan<32,36><<<16,256,128*33*2*4,stream>>>(rP0,rN0,bP0,bN0);
  keval0<<<256,256,0,stream>>>(ss0,sv0,bP0,bN0,hp0,pm0,eP0,eN0,b0,elu);
  // ---- layer 1 ----
  kstats<128><<<128,256,0,stream>>>(elu,st1);
  kproj1<<<256,256,0,stream>>>(elu,st1,w1,as1,ad1,hp1,ss1,sd1);
  ksort_runs<<<16,256,0,stream>>>(sd1,runs1);
  kmerge<<<16,1024,0,stream>>>(runs1,sv1,pm1,eP1,eN1);
  kchunksA<64,68,4><<<128,256,0,stream>>>(pm1,eP1,eN1,hp1,rP1,rN1);
  kscan<64,68><<<4,256,128*65*2*4,stream>>>(rP1,rN1,bP1,bN1);
  keval1<<<128,256,0,stream>>>(ss1,sv1,bP1,bN1,hp1,pm1,eP1,eN1,b1,out);
}

// Round 4
// 284.578 us; speedup vs baseline: 1.7617x; 1.1925x over previous
//
#include <hip/hip_runtime.h>
#include <math.h>

#define N_ 4096

// ---------------- workspace float offsets -----------------------------------
static constexpr size_t OFF_STATS0 = 0;        // [4][64][2]
static constexpr size_t OFF_STATS1 = 512;      // [4][128][2] (memset 1536 floats)
static constexpr size_t OFF_HP0    = 2048;     // [16][4096][32]
static constexpr size_t OFF_SS0    = 2099200;
static constexpr size_t OFF_SD0    = 2164736;
static constexpr size_t OFF_RUNS0  = 2230272;  // u64[16][4096]
static constexpr size_t OFF_SV0    = 2361344;
static constexpr size_t OFF_PM0    = 2426880;
static constexpr size_t OFF_EP0    = 2492416;
static constexpr size_t OFF_EN0    = 2557952;
static constexpr size_t OFF_RAWP0  = 2623488;  // [16][128][36]
static constexpr size_t OFF_RAWN0  = 2697216;
static constexpr size_t OFF_BP0    = 2770944;  // [16][129][36]
static constexpr size_t OFF_BN0    = 2845248;
static constexpr size_t OFF_ELU    = 2919552;  // [4][4096][128]
static constexpr size_t OFF_HP1    = 5016704;  // [4][4096][64]
static constexpr size_t OFF_SS1    = 6065280;
static constexpr size_t OFF_SD1    = 6081664;
static constexpr size_t OFF_RUNS1  = 6098048;  // u64[4][4096]
static constexpr size_t OFF_SV1    = 6130816;
static constexpr size_t OFF_PM1    = 6147200;
static constexpr size_t OFF_EP1    = 6163584;
static constexpr size_t OFF_EN1    = 6179968;
static constexpr size_t OFF_RAWP1  = 6196352;  // [4][128][68]
static constexpr size_t OFF_RAWN1  = 6231168;
static constexpr size_t OFF_BP1    = 6265984;  // [4][129][68]
static constexpr size_t OFF_BN1    = 6301072;  // end 6336160 floats ~= 25.3 MB

__device__ __forceinline__ unsigned f2s(float f){
  unsigned u=__float_as_uint(f);
  return u^((u&0x80000000u)?0xFFFFFFFFu:0x80000000u);
}
__device__ __forceinline__ float s2f(unsigned s){
  unsigned u=(s&0x80000000u)?(s^0x80000000u):~s;
  return __uint_as_float(u);
}

// ---------- partial stats (coalesced) + atomic accumulate --------------------
template<int C>
__global__ void kstats(const float* __restrict__ x, float* __restrict__ stats){
  int blk=blockIdx.x; int b=blk>>5, seg=blk&31;
  int tid=threadIdx.x;
  const int RPT=256/C;
  const int IT=128/RPT;
  int c=tid%C, rl=tid/C;
  const float* xb=x+(size_t)b*N_*C;
  float s1=0.f,s2=0.f;
  int r0=seg*128+rl;
  for(int i=0;i<IT;i++){
    float v=xb[(size_t)(r0+i*RPT)*C+c];
    s1+=v;s2+=v*v;
  }
  __shared__ float sh1[256],sh2[256];
  sh1[tid]=s1;sh2[tid]=s2;__syncthreads();
  if(tid<C){
    float a1=0.f,a2=0.f;
    for(int g=0;g<RPT;g++){a1+=sh1[g*C+tid];a2+=sh2[g*C+tid];}
    atomicAdd(&stats[(size_t)(b*C+tid)*2+0],a1);
    atomicAdd(&stats[(size_t)(b*C+tid)*2+1],a2);
  }
}

// ---------- layer0 projection, chunked k (no private row array, no spill) ----
__global__ void __launch_bounds__(256) kproj0(
                       const float* __restrict__ x, const float* __restrict__ stats,
                       const float* __restrict__ w0, const float* __restrict__ asrc,
                       const float* __restrict__ adst, float* __restrict__ hp,
                       float* __restrict__ ss, float* __restrict__ sd){
  __shared__ float4 w4[2048];        // [h][d][kq]: (h*64+d)*8+q
  __shared__ float4 av4[64];
  __shared__ float mean[64],rstd[64];
  int tid=threadIdx.x;
  const float4* wg=(const float4*)w0;
  for(int i=tid;i<2048;i+=256) w4[i]=wg[i];
  if(tid<32) av4[tid]=((const float4*)asrc)[tid];
  else if(tid<64) av4[tid]=((const float4*)adst)[tid-32];
  int gid=blockIdx.x*256+tid;
  int b=gid>>14;
  if(tid<64){
    float s1=stats[(size_t)(b*64+tid)*2+0],s2=stats[(size_t)(b*64+tid)*2+1];
    float mu=s1*(1.0f/N_);
    float var=s2*(1.0f/N_)-mu*mu;
    mean[tid]=mu; rstd[tid]=rsqrtf(var+1e-5f);
  }
  __syncthreads();
  int n=(gid>>2)&4095, h=gid&3;
  const float4* hr4=(const float4*)(x+((size_t)(b*N_+n))*64);
  float4 acc[8];
  #pragma unroll
  for(int q=0;q<8;q++) acc[q]=make_float4(0.f,0.f,0.f,0.f);
  #pragma unroll
  for(int ch=0;ch<4;ch++){
    float4 t[4];
    #pragma unroll
    for(int j=0;j<4;j++) t[j]=hr4[ch*4+j];
    #pragma unroll
    for(int j=0;j<4;j++){
      int d0=ch*16+j*4;
      float hv[4];
      hv[0]=(t[j].x-mean[d0+0])*rstd[d0+0];
      hv[1]=(t[j].y-mean[d0+1])*rstd[d0+1];
      hv[2]=(t[j].z-mean[d0+2])*rstd[d0+2];
      hv[3]=(t[j].w-mean[d0+3])*rstd[d0+3];
      #pragma unroll
      for(int dd=0;dd<4;dd++){
        float hvv=hv[dd];
        #pragma unroll
        for(int q=0;q<8;q++){
          float4 wv=w4[(h*64+d0+dd)*8+q];
          acc[q].x+=hvv*wv.x;acc[q].y+=hvv*wv.y;acc[q].z+=hvv*wv.z;acc[q].w+=hvv*wv.w;
        }
      }
    }
  }
  float ssv=0.f,sdv=0.f;
  #pragma unroll
  for(int q=0;q<8;q++){
    float4 a1=av4[h*8+q],a2=av4[32+h*8+q];
    ssv+=acc[q].x*a1.x+acc[q].y*a1.y+acc[q].z*a1.z+acc[q].w*a1.w;
    sdv+=acc[q].x*a2.x+acc[q].y*a2.y+acc[q].z*a2.z+acc[q].w*a2.w;
  }
  int p=b*4+h;
  float4* o4=(float4*)(hp+((size_t)p*N_+n)*32);
  #pragma unroll
  for(int q=0;q<8;q++) o4[q]=acc[q];
  ss[(size_t)p*N_+n]=ssv; sd[(size_t)p*N_+n]=sdv;
}

// ---------- layer1 projection, chunked k (no spill); s via folded w1@a -------
__global__ void __launch_bounds__(256) kproj1(
                       const float* __restrict__ x, const float* __restrict__ stats,
                       const float* __restrict__ w1, const float* __restrict__ asrc,
                       const float* __restrict__ adst, float* __restrict__ hp,
                       float* __restrict__ ss, float* __restrict__ sd){
  __shared__ float4 w4[2048];        // [d][k4]: d*16 + k4
  __shared__ float wa[128],wd[128],mean[128],rstd[128];
  int tid=threadIdx.x;
  const float4* wg=(const float4*)w1;
  for(int i=tid;i<2048;i+=256) w4[i]=wg[i];
  int gid=blockIdx.x*256+tid;
  int b=gid>>14;
  if(tid<128){
    float s1a=0.f,s2a=0.f;
    for(int k=0;k<64;k++){float wv=w1[tid*64+k];s1a+=wv*asrc[k];s2a+=wv*adst[k];}
    wa[tid]=s1a;wd[tid]=s2a;
    float s1=stats[(size_t)(b*128+tid)*2+0],s2=stats[(size_t)(b*128+tid)*2+1];
    float mu=s1*(1.0f/N_);
    float var=s2*(1.0f/N_)-mu*mu;
    mean[tid]=mu; rstd[tid]=rsqrtf(var+1e-5f);
  }
  __syncthreads();
  int n=(gid>>2)&4095, q4=gid&3;
  const float4* hr4=(const float4*)(x+((size_t)(b*N_+n))*128);
  float4 acc[4];
  #pragma unroll
  for(int q=0;q<4;q++) acc[q]=make_float4(0.f,0.f,0.f,0.f);
  float s1=0.f,s2=0.f;
  #pragma unroll
  for(int ch=0;ch<8;ch++){
    float4 t[4];
    #pragma unroll
    for(int j=0;j<4;j++) t[j]=hr4[ch*4+j];
    #pragma unroll
    for(int j=0;j<4;j++){
      int d0=ch*16+j*4;
      float hv[4];
      hv[0]=(t[j].x-mean[d0+0])*rstd[d0+0];
      hv[1]=(t[j].y-mean[d0+1])*rstd[d0+1];
      hv[2]=(t[j].z-mean[d0+2])*rstd[d0+2];
      hv[3]=(t[j].w-mean[d0+3])*rstd[d0+3];
      #pragma unroll
      for(int dd=0;dd<4;dd++){
        float hvv=hv[dd]; int d=d0+dd;
        s1+=hvv*wa[d]; s2+=hvv*wd[d];
        #pragma unroll
        for(int q=0;q<4;q++){
          float4 wv=w4[d*16+q4*4+q];
          acc[q].x+=hvv*wv.x;acc[q].y+=hvv*wv.y;acc[q].z+=hvv*wv.z;acc[q].w+=hvv*wv.w;
        }
      }
    }
  }
  float4* o4=(float4*)(hp+((size_t)(b*N_+n))*64+q4*16);
  #pragma unroll
  for(int q=0;q<4;q++) o4[q]=acc[q];
  if(q4==0){
    ss[(size_t)b*N_+n]=s1;sd[(size_t)b*N_+n]=s2;
  }
}

// ---------- sort runs of 1024 (packed u64 = key<<32 | orig_idx) --------------
__global__ void __launch_bounds__(256) ksort_runs(const float* __restrict__ sdst,
                                                  unsigned long long* __restrict__ runs){
  __shared__ unsigned long long sm[1024];
  int p=blockIdx.x>>2, run=blockIdx.x&3;
  int tid=threadIdx.x;
  const float* s=sdst+(size_t)p*N_+run*1024;
  for(int l=tid;l<1024;l+=256){
    unsigned key=f2s(s[l]);
    sm[l]=((unsigned long long)key<<32)|(unsigned)(run*1024+l);
  }
  for(unsigned k=2;k<=1024u;k<<=1)
    for(unsigned j=k>>1;j>0;j>>=1){
      __syncthreads();
      for(unsigned t=tid;t<512u;t+=256u){
        unsigned i=((t&~(j-1))<<1)|(t&(j-1));
        unsigned q=i|j;
        bool up=((i&k)==0);
        unsigned long long a=sm[i],b=sm[q];
        if((a>b)==up){sm[i]=b;sm[q]=a;}
      }
    }
  __syncthreads();
  unsigned long long* rg=runs+(size_t)p*N_+run*1024;
  for(int l=tid;l<1024;l+=256) rg[l]=sm[l];
}

// ---------- merge 4 sorted runs by rank (binary search in LDS) ---------------
__global__ void __launch_bounds__(1024) kmerge(const unsigned long long* __restrict__ runs,
    float* __restrict__ sv, unsigned* __restrict__ perm,
    float* __restrict__ eP, float* __restrict__ eN){
  __shared__ unsigned long long sm[4096];
  int p=blockIdx.x>>2, cg=blockIdx.x&3;
  int tid=threadIdx.x;
  const unsigned long long* rg=runs+(size_t)p*N_;
  for(int l=tid;l<4096;l+=1024) sm[l]=rg[l];
  __syncthreads();
  unsigned long long e=sm[cg*1024+tid];
  int rank=tid;
  #pragma unroll
  for(int o=0;o<4;o++){
    if(o==cg) continue;
    const unsigned long long* base=sm+o*1024;
    int lo=0,hi=1024;
    while(lo<hi){int mid=(lo+hi)>>1; if(base[mid]<e) lo=mid+1; else hi=mid;}
    rank+=lo;
  }
  unsigned long long mk=sm[1023];
  if(sm[2047]>mk) mk=sm[2047];
  if(sm[3071]>mk) mk=sm[3071];
  if(sm[4095]>mk) mk=sm[4095];
  float m=s2f((unsigned)(mk>>32));
  float v=s2f((unsigned)(e>>32));
  size_t o=(size_t)p*N_+rank;
  sv[o]=v;
  perm[o]=(unsigned)(e&0xffffffffu);
  eP[o]=expf(v-m);
  eN[o]=expf(0.2f*(v-m));
}

// ---------- chunk sums (32-rank chunks), occupancy-spread --------------------
template<int D,int DPAD,int CPB>
__global__ void __launch_bounds__(256) kchunksA(const unsigned* __restrict__ perm,
    const float* __restrict__ eP, const float* __restrict__ eN,
    const float* __restrict__ hp, float* __restrict__ rawP, float* __restrict__ rawN){
  const int G=128/CPB;
  int p=blockIdx.x/G, cg=blockIdx.x%G;
  int tid=threadIdx.x;
  __shared__ unsigned pmL[CPB*32];
  __shared__ float ePL[CPB*32],eNL[CPB*32];
  int r0=cg*CPB*32;
  for(int i=tid;i<CPB*32;i+=256){
    pmL[i]=perm[(size_t)p*N_+r0+i];
    ePL[i]=eP[(size_t)p*N_+r0+i];
    eNL[i]=eN[(size_t)p*N_+r0+i];
  }
  __syncthreads();
  const float* hb=hp+(size_t)p*N_*D;
  for(int tt=tid;tt<CPB*(D+1);tt+=256){
    int cl=tt/(D+1), kk=tt%(D+1);
    float sp=0.f,sn=0.f;
    #pragma unroll 4
    for(int q=0;q<32;q++){
      int rl=cl*32+q;
      float hv=(kk<D)?hb[(size_t)pmL[rl]*D+kk]:1.0f;
      sp+=ePL[rl]*hv; sn+=eNL[rl]*hv;
    }
    int c=cg*CPB+cl;
    rawP[((size_t)p*128+c)*DPAD+kk]=sp;
    rawN[((size_t)p*128+c)*DPAD+kk]=sn;
  }
}

// ---------- exclusive scan over 128 chunks, entirely in LDS ------------------
template<int D,int DPAD>
__global__ void __launch_bounds__(256) kscan(const float* __restrict__ rawP,
    const float* __restrict__ rawN, float* __restrict__ bP, float* __restrict__ bN){
  extern __shared__ float sm[];
  float* smP=sm;
  float* smN=sm+128*(D+1);
  int p=blockIdx.x, tid=threadIdx.x;
  for(int i=tid;i<128*(D+1);i+=256){
    int c=i/(D+1), kk=i%(D+1);
    smP[i]=rawP[((size_t)p*128+c)*DPAD+kk];
    smN[i]=rawN[((size_t)p*128+c)*DPAD+kk];
  }
  __syncthreads();
  if(tid<2*(D+1)){
    int kk=tid>>1;
    const float* s=(tid&1)?smN:smP;
    float* g=(tid&1)?bN:bP;
    float r=0.f;
    for(int c=0;c<128;c++){
      g[((size_t)p*129+c)*DPAD+kk]=r;
      r+=s[c*(D+1)+kk];
    }
    g[((size_t)p*129+128)*DPAD+kk]=r;
  }
}

// ---------- layer0 row eval: bases + residual, +bias, ELU, head-concat -------
__global__ void keval0(const float* __restrict__ ss, const float* __restrict__ sv,
                       const float* __restrict__ bP, const float* __restrict__ bN,
                       const float* __restrict__ hp, const unsigned* __restrict__ perm,
                       const float* __restrict__ eP, const float* __restrict__ eN,
                       const float* __restrict__ bias, float* __restrict__ out){
  int gid=blockIdx.x*256+threadIdx.x;
  int p=gid>>12, i=gid&4095;
  int b=p>>2,h=p&3;
  const float* svp=sv+(size_t)p*N_;
  float ssrc=ss[(size_t)p*N_+i];
  float m=svp[4095];
  float xx=ssrc+m;
  float M=xx>0.f?xx:0.2f*xx;
  float fpos=expf(xx-M),fneg=expf(0.2f*xx-M);
  float th=-ssrc;
  int lo=0,hi=4096;
  while(lo<hi){int mid=(lo+hi)>>1; if(svp[mid]<=th) lo=mid+1; else hi=mid;}
  int c=lo>>5;
  float4 aP[8],aN[8];
  #pragma unroll
  for(int q=0;q<8;q++){aP[q]=make_float4(0.f,0.f,0.f,0.f);aN[q]=make_float4(0.f,0.f,0.f,0.f);}
  float aPd=0.f,aNd=0.f;
  for(int r=c*32;r<lo;r++){
    unsigned pr=perm[(size_t)p*N_+r];
    float ep=eP[(size_t)p*N_+r],en=eN[(size_t)p*N_+r];
    const float4* hr=(const float4*)(hp+((size_t)p*N_+pr)*32);
    aPd+=ep;aNd+=en;
    #pragma unroll
    for(int q=0;q<8;q++){
      float4 hv=hr[q];
      aP[q].x+=ep*hv.x;aP[q].y+=ep*hv.y;aP[q].z+=ep*hv.z;aP[q].w+=ep*hv.w;
      aN[q].x+=en*hv.x;aN[q].y+=en*hv.y;aN[q].z+=en*hv.z;aN[q].w+=en*hv.w;
    }
  }
  const float* bp=bP+((size_t)p*129+c)*36;
  const float* bn=bN+((size_t)p*129+c)*36;
  const float* tp=bP+((size_t)p*129+128)*36;
  float denom=fpos*(tp[32]-(bp[32]+aPd))+fneg*(bn[32]+aNd);
  float inv=1.0f/denom;
  float* op=out+((size_t)(b*N_+i))*128+h*32;
  #pragma unroll
  for(int q=0;q<8;q++){
    float4 B4=((const float4*)bp)[q],Bn4=((const float4*)bn)[q],T4=((const float4*)tp)[q];
    float4 r;
    r.x=(fpos*(T4.x-(B4.x+aP[q].x))+fneg*(Bn4.x+aN[q].x))*inv+bias[4*q+0];
    r.y=(fpos*(T4.y-(B4.y+aP[q].y))+fneg*(Bn4.y+aN[q].y))*inv+bias[4*q+1];
    r.z=(fpos*(T4.z-(B4.z+aP[q].z))+fneg*(Bn4.z+aN[q].z))*inv+bias[4*q+2];
    r.w=(fpos*(T4.w-(B4.w+aP[q].w))+fneg*(Bn4.w+aN[q].w))*inv+bias[4*q+3];
    r.x=r.x>0.f?r.x:expm1f(r.x);
    r.y=r.y>0.f?r.y:expm1f(r.y);
    r.z=r.z>0.f?r.z:expm1f(r.z);
    r.w=r.w>0.f?r.w:expm1f(r.w);
    ((float4*)op)[q]=r;
  }
}

// ---------- layer1 row eval (split channels in half per thread) --------------
__global__ void keval1(const float* __restrict__ ss, const float* __restrict__ sv,
                       const float* __restrict__ bP, const float* __restrict__ bN,
                       const float* __restrict__ hp, const unsigned* __restrict__ perm,
                       const float* __restrict__ eP, const float* __restrict__ eN,
                       const float* __restrict__ bias, float* __restrict__ out){
  int gid=blockIdx.x*256+threadIdx.x;
  int kb=gid&1, i=(gid>>1)&4095, p=gid>>13;
  const float* svp=sv+(size_t)p*N_;
  float ssrc=ss[(size_t)p*N_+i];
  float m=svp[4095];
  float xx=ssrc+m;
  float M=xx>0.f?xx:0.2f*xx;
  float fpos=expf(xx-M),fneg=expf(0.2f*xx-M);
  float th=-ssrc;
  int lo=0,hi=4096;
  while(lo<hi){int mid=(lo+hi)>>1; if(svp[mid]<=th) lo=mid+1; else hi=mid;}
  int c=lo>>5;
  float4 aP[8],aN[8];
  #pragma unroll
  for(int q=0;q<8;q++){aP[q]=make_float4(0.f,0.f,0.f,0.f);aN[q]=make_float4(0.f,0.f,0.f,0.f);}
  float aPd=0.f,aNd=0.f;
  for(int r=c*32;r<lo;r++){
    unsigned pr=perm[(size_t)p*N_+r];
    float ep=eP[(size_t)p*N_+r],en=eN[(size_t)p*N_+r];
    const float4* hr=(const float4*)(hp+((size_t)p*N_+pr)*64+kb*32);
    aPd+=ep;aNd+=en;
    #pragma unroll
    for(int q=0;q<8;q++){
      float4 hv=hr[q];
      aP[q].x+=ep*hv.x;aP[q].y+=ep*hv.y;aP[q].z+=ep*hv.z;aP[q].w+=ep*hv.w;
      aN[q].x+=en*hv.x;aN[q].y+=en*hv.y;aN[q].z+=en*hv.z;aN[q].w+=en*hv.w;
    }
  }
  const float* bpr=bP+((size_t)p*129+c)*68;
  const float* bnr=bN+((size_t)p*129+c)*68;
  const float* tpr=bP+((size_t)p*129+128)*68;
  float denom=fpos*(tpr[64]-(bpr[64]+aPd))+fneg*(bnr[64]+aNd);
  float inv=1.0f/denom;
  const float* bp=bpr+kb*32;
  const float* bn=bnr+kb*32;
  const float* tp=tpr+kb*32;
  const float* bi=bias+kb*32;
  float* op=out+((size_t)p*N_+i)*64+kb*32;
  #pragma unroll
  for(int q=0;q<8;q++){
    float4 B4=((const float4*)bp)[q],Bn4=((const float4*)bn)[q],T4=((const float4*)tp)[q];
    float4 r;
    r.x=(fpos*(T4.x-(B4.x+aP[q].x))+fneg*(Bn4.x+aN[q].x))*inv+bi[4*q+0];
    r.y=(fpos*(T4.y-(B4.y+aP[q].y))+fneg*(Bn4.y+aN[q].y))*inv+bi[4*q+1];
    r.z=(fpos*(T4.z-(B4.z+aP[q].z))+fneg*(Bn4.z+aN[q].z))*inv+bi[4*q+2];
    r.w=(fpos*(T4.w-(B4.w+aP[q].w))+fneg*(Bn4.w+aN[q].w))*inv+bi[4*q+3];
    ((float4*)op)[q]=r;
  }
}

extern "C" void kernel_launch(void* const* d_in, const int* in_sizes, int n_in,
                              void* d_out, int out_size, void* d_ws, size_t ws_size,
                              hipStream_t stream) {
  const float* x  =(const float*)d_in[0];
  const float* w0 =(const float*)d_in[1];
  const float* as0=(const float*)d_in[2];
  const float* ad0=(const float*)d_in[3];
  const float* b0 =(const float*)d_in[4];
  const float* w1 =(const float*)d_in[5];
  const float* as1=(const float*)d_in[6];
  const float* ad1=(const float*)d_in[7];
  const float* b1 =(const float*)d_in[8];
  float* ws=(float*)d_ws;
  float* out=(float*)d_out;

  float* st0 = ws+OFF_STATS0;
  float* st1 = ws+OFF_STATS1;
  float* hp0 = ws+OFF_HP0;
  float* ss0 = ws+OFF_SS0;  float* sd0 = ws+OFF_SD0;
  unsigned long long* runs0=(unsigned long long*)(ws+OFF_RUNS0);
  float* sv0 = ws+OFF_SV0;
  unsigned* pm0=(unsigned*)(ws+OFF_PM0);
  float* eP0 = ws+OFF_EP0;  float* eN0 = ws+OFF_EN0;
  float* rP0 = ws+OFF_RAWP0; float* rN0 = ws+OFF_RAWN0;
  float* bP0 = ws+OFF_BP0;  float* bN0 = ws+OFF_BN0;
  float* elu = ws+OFF_ELU;
  float* hp1 = ws+OFF_HP1;
  float* ss1 = ws+OFF_SS1;  float* sd1 = ws+OFF_SD1;
  unsigned long long* runs1=(unsigned long long*)(ws+OFF_RUNS1);
  float* sv1 = ws+OFF_SV1;
  unsigned* pm1=(unsigned*)(ws+OFF_PM1);
  float* eP1 = ws+OFF_EP1;  float* eN1 = ws+OFF_EN1;
  float* rP1 = ws+OFF_RAWP1; float* rN1 = ws+OFF_RAWN1;
  float* bP1 = ws+OFF_BP1;  float* bN1 = ws+OFF_BN1;

  hipMemsetAsync(d_ws, 0, 1536*sizeof(float), stream);

  // ---- layer 0 ----
  kstats<64><<<128,256,0,stream>>>(x,st0);
  kproj0<<<256,256,0,stream>>>(x,st0,w0,as0,ad0,hp0,ss0,sd0);
  ksort_runs<<<64,256,0,stream>>>(sd0,runs0);
  kmerge<<<64,1024,0,stream>>>(runs0,sv0,pm0,eP0,eN0);
  kchunksA<32,36,8><<<256,256,0,stream>>>(pm0,eP0,eN0,hp0,rP0,rN0);
  kscan<32,36><<<16,256,128*33*2*4,stream>>>(rP0,rN0,bP0,bN0);
  keval0<<<256,256,0,stream>>>(ss0,sv0,bP0,bN0,hp0,pm0,eP0,eN0,b0,elu);
  // ---- layer 1 ----
  kstats<128><<<128,256,0,stream>>>(elu,st1);
  kproj1<<<256,256,0,stream>>>(elu,st1,w1,as1,ad1,hp1,ss1,sd1);
  ksort_runs<<<16,256,0,stream>>>(sd1,runs1);
  kmerge<<<16,1024,0,stream>>>(runs1,sv1,pm1,eP1,eN1);
  kchunksA<64,68,4><<<128,256,0,stream>>>(pm1,eP1,eN1,hp1,rP1,rN1);
  kscan<64,68><<<4,256,128*65*2*4,stream>>>(rP1,rN1,bP1,bN1);
  keval1<<<128,256,0,stream>>>(ss1,sv1,bP1,bN1,hp1,pm1,eP1,eN1,b1,out);
}